// Round 10
// baseline (1420.685 us; speedup 1.0000x reference)
//
#include <hip/hip_runtime.h>
#include <hip/hip_bf16.h>
#include <math.h>

#define MDIM 32768
#define NDIM 2048
#define KDIM 2048

typedef __attribute__((ext_vector_type(8))) short bf16x8;
typedef __attribute__((ext_vector_type(4))) float f32x4;

__device__ __forceinline__ unsigned short f2bf(float f) {
  unsigned int u = __float_as_uint(f);
  u += 0x7FFFu + ((u >> 16) & 1u);
  return (unsigned short)(u >> 16);
}
__device__ __forceinline__ float bf2f(unsigned short b) {
  return __uint_as_float(((unsigned int)b) << 16);
}

__device__ __forceinline__ void gll16(const void* g, void* l) {
  __builtin_amdgcn_global_load_lds((__attribute__((address_space(1))) void*)g,
                                   (__attribute__((address_space(3))) void*)l,
                                   16, 0, 0);
}

// ---------------- split x into bf16 hi/lo ----------------
__global__ void split_x_kernel(const float4* __restrict__ x, ushort4* __restrict__ xhi,
                               ushort4* __restrict__ xlo, int n4) {
  int stride = gridDim.x * blockDim.x;
  for (int i = blockIdx.x * blockDim.x + threadIdx.x; i < n4; i += stride) {
    float4 v = x[i];
    ushort4 h, l;
    h.x = f2bf(v.x); l.x = f2bf(v.x - bf2f(h.x));
    h.y = f2bf(v.y); l.y = f2bf(v.y - bf2f(h.y));
    h.z = f2bf(v.z); l.z = f2bf(v.z - bf2f(h.z));
    h.w = f2bf(v.w); l.w = f2bf(v.w - bf2f(h.w));
    xhi[i] = h; xlo[i] = l;
  }
}

// ---------------- transpose + split W1 -> WT (N x K) hi/lo ----------------
__global__ void split_wT_kernel(const float* __restrict__ w1, unsigned short* __restrict__ wthi,
                                unsigned short* __restrict__ wtlo) {
  __shared__ float tile[32][33];
  int bx = blockIdx.x, by = blockIdx.y;
  int tx = threadIdx.x, ty = threadIdx.y;  // (32, 8)
#pragma unroll
  for (int r = 0; r < 4; ++r) {
    int d = by * 32 + ty + r * 8;
    tile[ty + r * 8][tx] = w1[(size_t)d * NDIM + bx * 32 + tx];
  }
  __syncthreads();
#pragma unroll
  for (int r = 0; r < 4; ++r) {
    int h = bx * 32 + ty + r * 8;
    float v = tile[tx][ty + r * 8];
    unsigned short hi = f2bf(v);
    unsigned short lo = f2bf(v - bf2f(hi));
    size_t o = (size_t)h * KDIM + by * 32 + tx;
    wthi[o] = hi; wtlo[o] = lo;
  }
}

// ---------------- fused GEMM: A via LDS ring, B global->regs ----------------
// logits[m] = sum_n relu(sum_k x[m,k] W1[k,n] + b1[n]) * W2[n]
// 3-product split: kt 0..31: xhi*wthi ; 32..63: xhi*wtlo ; 64..95: xlo*wthi.
// BM=BN=256, BK=64, 8 waves, 1 block/CU. LDS = 8-slot ring of A HALF-tiles
// only (16 KB each, swizzled); half h = 2*kt + {0,1}, slot h&7 -> 4-tile
// period. B fragments are loaded global->regs (L2-resident per-kt slices),
// double-buffered one tile ahead (bA/bB ping-pong, loop unrolled x2).
// Per tile TWO phases of 32 MFMA:
//   phA: stage A[kt+3] (4 gll16) + load B[kt+1] (8 loads) ; Q00,Q01 on a=A0;
//        fill a<-A1[kt] ; vmcnt(12)+barrier
//   phB: Q11,Q10 on a=A1 ; fill a<-A0[kt+1] ; vmcnt(12)+barrier
// Hazard ledger: every fill's slot was staged 2-3 tiles earlier (landed via
// the vmcnt(12)-per-tile cadence: at any barrier, everything older than the
// current tile's 12 issues has landed, cross-wave via the barrier); every
// slot overwrite is >=2 barriers after its last ds_read with the consuming
// MFMA (compiler lgkm wait) in between — same distances as the proven
// round-4 ledger. B-reg waits are compiler-inserted (C loads); asm memory
// clobbers pin them into their phase.
__global__ __launch_bounds__(512, 2) void gemm8(
    const unsigned short* __restrict__ xhi, const unsigned short* __restrict__ xlo,
    const unsigned short* __restrict__ wthi, const unsigned short* __restrict__ wtlo,
    const float* __restrict__ b1, const float* __restrict__ w2,
    float* __restrict__ part) {
  __shared__ char lds[8 * 16384];   // 128 KiB ring (A halves only)

  const int t = threadIdx.x;
  const int l = t & 63;
  const int w = t >> 6;
  const int sub_m = w >> 2, sub_n = w & 3;
  const int r16 = l & 15;
  const int q4 = l >> 4;

  // XCD-chunked bijective swizzle: 1024 blocks = 8 XCDs x 128
  int bid = blockIdx.x;
  int id = (bid & 7) * 128 + (bid >> 3);
  const int bm = id >> 3, bn = id & 7;
  const int m0 = bm * 256, n0 = bn * 256;

  // staging per-thread constants
  const int tr = t >> 3;                                  // 0..63
  const int cs16 = (((t & 7) ^ ((t >> 3) & 7)) << 4);     // swizzled chunk byte
  const int t16 = t << 4;

  // LDS read-side constants (A fragments)
  const int axor = (l & 7) << 4;
  const int akoff = ((l >> 4) & 3) << 4;
  const int a_row0 = sub_m * 64 + r16;

  // B global-load constants
  const int koff8 = ((l >> 4) & 3) * 8;                   // element offset in k
  const int nrow0 = n0 + sub_n * 32 + r16;                // fn=0 row

// stage one A half-tile (h = 2*kt + half) into slot h&7
#define STAGE(hh_)                                                             \
  {                                                                            \
    int h_ = (hh_);                                                            \
    if (h_ < 192) {                                                            \
      int jt = h_ >> 1;                                                        \
      const unsigned short* base = (jt < 64) ? xhi : xlo;                      \
      int k0 = (jt & 31) << 6;                                                 \
      int row0 = m0 + ((h_ & 1) << 7);                                         \
      char* dst = lds + ((h_ & 7) << 14) + t16;                                \
      const char* src = (const char*)base +                                    \
          ((((size_t)(row0 + tr)) << 11) + (size_t)k0) * 2 + cs16;             \
      gll16(src, dst);                                                         \
      gll16(src + (64ull << 12), dst + 8192);                                  \
    }                                                                          \
  }

#define LDA(slot)                                                              \
  _Pragma("unroll")                                                            \
  for (int fm = 0; fm < 4; ++fm)                                               \
    _Pragma("unroll")                                                          \
    for (int kk = 0; kk < 2; ++kk)                                             \
      a[fm][kk] = *(const bf16x8*)(lds + ((slot) << 14) +                      \
          (a_row0 + fm * 16) * 128 + (((kk << 6) | akoff) ^ axor));

// load ALL B fragments of tile ktn into dst[2][2][2] ([nh][fn][kk])
#define BLOAD(dst, ktn)                                                        \
  {                                                                            \
    int kq_ = (ktn);                                                           \
    const unsigned short* bb_ = (kq_ < 32 || kq_ >= 64) ? wthi : wtlo;         \
    int k0_ = ((kq_ & 31) << 6) + koff8;                                       \
    _Pragma("unroll")                                                          \
    for (int nh = 0; nh < 2; ++nh)                                             \
      _Pragma("unroll")                                                        \
      for (int fn = 0; fn < 2; ++fn)                                           \
        _Pragma("unroll")                                                      \
        for (int kk = 0; kk < 2; ++kk)                                         \
          dst[nh][fn][kk] = *(const bf16x8*)(bb_ +                             \
              (((size_t)(nrow0 + nh * 128 + fn * 16)) << 11) + k0_ + kk * 32); \
  }

#define MFMA16(accq, bb)                                                       \
  _Pragma("unroll")                                                            \
  for (int fm = 0; fm < 4; ++fm)                                               \
    _Pragma("unroll")                                                          \
    for (int fn = 0; fn < 2; ++fn) {                                           \
      accq[fm][fn] = __builtin_amdgcn_mfma_f32_16x16x32_bf16(a[fm][0], bb[fn][0], accq[fm][fn], 0, 0, 0); \
      accq[fm][fn] = __builtin_amdgcn_mfma_f32_16x16x32_bf16(a[fm][1], bb[fn][1], accq[fm][fn], 0, 0, 0); \
    }

#define WAITBAR                                                                \
  asm volatile("s_waitcnt vmcnt(12)" ::: "memory");                            \
  __builtin_amdgcn_s_barrier();                                                \
  asm volatile("" ::: "memory");

  f32x4 acc00[4][2], acc01[4][2], acc11[4][2], acc10[4][2];
  f32x4 zero = {0.f, 0.f, 0.f, 0.f};
#pragma unroll
  for (int i = 0; i < 4; ++i)
#pragma unroll
    for (int j = 0; j < 2; ++j) {
      acc00[i][j] = zero; acc01[i][j] = zero;
      acc11[i][j] = zero; acc10[i][j] = zero;
    }

  bf16x8 a[4][2], bA[2][2][2], bB[2][2][2];

  // prologue: stage A halves of tiles 0..2 (slots 0..5), load B[0] into bA;
  // vmcnt(0)+barrier -> ALL waves' stages landed (cross-wave); read a=A0[0].
  // First loop STAGEs write slots 6,7 -> no WAR with prologue reads.
  STAGE(0); STAGE(1); STAGE(2); STAGE(3); STAGE(4); STAGE(5);
  BLOAD(bA, 0);
  asm volatile("s_waitcnt vmcnt(0)" ::: "memory");
  __builtin_amdgcn_s_barrier();
  asm volatile("" ::: "memory");
  LDA(0);          // a = A0[0]

  for (int kt2 = 0; kt2 < 48; ++kt2) {
    const int kte = kt2 * 2, kto = kte + 1;
    // ---- tile kte: B in bA; prefetch B[kte+1] -> bB ----
    STAGE(2 * kte + 6); STAGE(2 * kte + 7);     // A[kte+3]
    BLOAD(bB, kte + 1);
    __builtin_amdgcn_s_setprio(1);
    MFMA16(acc00, bA[0]);
    MFMA16(acc01, bA[1]);
    __builtin_amdgcn_s_setprio(0);
    LDA((2 * kte + 1) & 7);                     // a <- A1[kte]
    WAITBAR;
    __builtin_amdgcn_s_setprio(1);
    MFMA16(acc11, bA[1]);
    MFMA16(acc10, bA[0]);
    __builtin_amdgcn_s_setprio(0);
    LDA((2 * kte + 2) & 7);                     // a <- A0[kte+1]
    WAITBAR;
    // ---- tile kto: B in bB; prefetch B[kto+1] -> bA ----
    STAGE(2 * kto + 6); STAGE(2 * kto + 7);     // A[kto+3]
    BLOAD(bA, kto + 1);                          // kto+1==96 harmless (unused)
    __builtin_amdgcn_s_setprio(1);
    MFMA16(acc00, bB[0]);
    MFMA16(acc01, bB[1]);
    __builtin_amdgcn_s_setprio(0);
    LDA((2 * kto + 1) & 7);                     // a <- A1[kto]
    WAITBAR;
    __builtin_amdgcn_s_setprio(1);
    MFMA16(acc11, bB[1]);
    MFMA16(acc10, bB[0]);
    __builtin_amdgcn_s_setprio(0);
    LDA((2 * kto + 2) & 7);                     // a <- A0[kto+1] (stale at end)
    WAITBAR;
  }

  // drain all staging before reusing LDS
  asm volatile("s_waitcnt vmcnt(0) lgkmcnt(0)" ::: "memory");
  __builtin_amdgcn_s_barrier();
  asm volatile("" ::: "memory");

  // epilogue: relu(acc + b1) * w2, reduce over n
  float b1v[2][2], w2v[2][2];
#pragma unroll
  for (int nh = 0; nh < 2; ++nh)
#pragma unroll
    for (int fn = 0; fn < 2; ++fn) {
      int n = n0 + nh * 128 + sub_n * 32 + fn * 16 + r16;
      b1v[nh][fn] = b1[n];
      w2v[nh][fn] = w2[n];
    }

  float* red = (float*)lds;   // 4 x 256 floats
#pragma unroll
  for (int mh = 0; mh < 2; ++mh)
#pragma unroll
    for (int fm = 0; fm < 4; ++fm)
#pragma unroll
      for (int j = 0; j < 4; ++j) {
        float s = 0.f;
#pragma unroll
        for (int fn = 0; fn < 2; ++fn) {
          float h0 = (mh == 0 ? acc00[fm][fn][j] : acc10[fm][fn][j]) + b1v[0][fn];
          s += fmaxf(h0, 0.f) * w2v[0][fn];
          float h1 = (mh == 0 ? acc01[fm][fn][j] : acc11[fm][fn][j]) + b1v[1][fn];
          s += fmaxf(h1, 0.f) * w2v[1][fn];
        }
        s += __shfl_xor(s, 1);
        s += __shfl_xor(s, 2);
        s += __shfl_xor(s, 4);
        s += __shfl_xor(s, 8);
        if (r16 == 0)
          red[sub_n * 256 + mh * 128 + sub_m * 64 + fm * 16 + q4 * 4 + j] = s;
      }
  __syncthreads();
  if (t < 256) {
    float p = red[t] + red[256 + t] + red[512 + t] + red[768 + t];
    part[(size_t)(m0 + t) * 8 + bn] = p;
  }
#undef STAGE
#undef LDA
#undef BLOAD
#undef MFMA16
#undef WAITBAR
}

// ---------------- per-batch-row: expected_k, top-k mask ----------------
__global__ void rowstats(const float* __restrict__ part, const float* __restrict__ b2,
                         float* __restrict__ mask_out, float* __restrict__ ek_out) {
  __shared__ float vals[2048];
  __shared__ float srt[2048];
  __shared__ float redf[256];
  __shared__ int redi[256];
  int b = blockIdx.x, t = threadIdx.x;
  float b2v = b2[0];
  float psum = 0.f;
  for (int i = t; i < 2048; i += 256) {
    const float* pp = part + ((size_t)b * 2048 + i) * 8;
    float v = pp[0] + pp[1] + pp[2] + pp[3] + pp[4] + pp[5] + pp[6] + pp[7] + b2v;
    vals[i] = v; srt[i] = v;
    psum += 1.f / (1.f + expf(-v));
  }
  redf[t] = psum;
  __syncthreads();
  for (int s = 128; s > 0; s >>= 1) {
    if (t < s) redf[t] += redf[t + s];
    __syncthreads();
  }
  float ek = redf[0];
  int k = (int)ek;
  if (k < 32) k = 32;
  if (k > 2048) k = 2048;
  if (t == 0) ek_out[b] = ek;

  for (int ksz = 2; ksz <= 2048; ksz <<= 1) {
    for (int j = ksz >> 1; j > 0; j >>= 1) {
      for (int i = t; i < 2048; i += 256) {
        int ixj = i ^ j;
        if (ixj > i) {
          float a = srt[i], c = srt[ixj];
          bool up = ((i & ksz) == 0);
          if ((a > c) == up) { srt[i] = c; srt[ixj] = a; }
        }
      }
      __syncthreads();
    }
  }
  float thr = srt[2048 - k];

  int cnt = 0;
  for (int i = t; i < 2048; i += 256) cnt += (vals[i] > thr) ? 1 : 0;
  redi[t] = cnt;
  __syncthreads();
  for (int s = 128; s > 0; s >>= 1) {
    if (t < s) redi[t] += redi[t + s];
    __syncthreads();
  }
  int n_gt = redi[0];
  int need = k - n_gt;

  for (int i = t; i < 2048; i += 256) {
    float v = vals[i];
    float m = 0.f;
    if (v > thr) m = 1.f;
    else if (v == thr) {
      int pre = 0;
      for (int p = 0; p < i; ++p) pre += (vals[p] == thr) ? 1 : 0;
      if (pre < need) m = 1.f;
    }
    mask_out[(size_t)b * 2048 + i] = m;
  }
}

// ---------------- filtered = x * mask ----------------
__global__ void filter_k(const float4* __restrict__ x, const float* __restrict__ mask,
                         float4* __restrict__ out, int n4) {
  int stride = gridDim.x * blockDim.x;
  for (int i = blockIdx.x * blockDim.x + threadIdx.x; i < n4; i += stride) {
    float m = mask[i >> 9];
    float4 v = x[i];
    v.x *= m; v.y *= m; v.z *= m; v.w *= m;
    out[i] = v;
  }
}

extern "C" void kernel_launch(void* const* d_in, const int* in_sizes, int n_in,
                              void* d_out, int out_size, void* d_ws, size_t ws_size,
                              hipStream_t stream) {
  const float* x  = (const float*)d_in[0];
  const float* w1 = (const float*)d_in[1];
  const float* b1 = (const float*)d_in[2];
  const float* w2 = (const float*)d_in[3];
  const float* b2 = (const float*)d_in[4];

  float* out_filt = (float*)d_out;
  float* out_mask = out_filt + (size_t)67108864;
  float* out_ek   = out_mask + 32768;

  unsigned short* xhi = (unsigned short*)d_out;   // parked in out0 region

  char* wsb = (char*)d_ws;
  unsigned short* xlo  = (unsigned short*)wsb;                      // 134217728 B
  unsigned short* wthi = (unsigned short*)(wsb + 134217728);        // 8388608 B
  unsigned short* wtlo = (unsigned short*)(wsb + 142606336);        // 8388608 B
  float* part   = (float*)(wsb + 150994944);                        // 1048576 B used

  split_x_kernel<<<dim3(4096), dim3(256), 0, stream>>>(
      (const float4*)x, (ushort4*)xhi, (ushort4*)xlo, 16777216);
  split_wT_kernel<<<dim3(64, 64), dim3(32, 8), 0, stream>>>(w1, wthi, wtlo);
  gemm8<<<dim3(1024), dim3(512), 0, stream>>>(
      xhi, xlo, wthi, wtlo, b1, w2, part);
  rowstats<<<dim3(16), dim3(256), 0, stream>>>(part, b2, out_mask, out_ek);
  filter_k<<<dim3(4096), dim3(256), 0, stream>>>(
      (const float4*)x, out_mask, (float4*)out_filt, 16777216);
}

// Round 11
// 965.875 us; speedup vs baseline: 1.4709x; 1.4709x over previous
//
#include <hip/hip_runtime.h>
#include <hip/hip_bf16.h>
#include <math.h>

#define MDIM 32768
#define NDIM 2048
#define KDIM 2048

typedef __attribute__((ext_vector_type(8))) short bf16x8;
typedef __attribute__((ext_vector_type(4))) float f32x4;

__device__ __forceinline__ unsigned short f2bf(float f) {
  unsigned int u = __float_as_uint(f);
  u += 0x7FFFu + ((u >> 16) & 1u);
  return (unsigned short)(u >> 16);
}
__device__ __forceinline__ float bf2f(unsigned short b) {
  return __uint_as_float(((unsigned int)b) << 16);
}

__device__ __forceinline__ void gll16(const void* g, void* l) {
  __builtin_amdgcn_global_load_lds((__attribute__((address_space(1))) void*)g,
                                   (__attribute__((address_space(3))) void*)l,
                                   16, 0, 0);
}

// ---------------- split x into bf16 hi/lo ----------------
__global__ void split_x_kernel(const float4* __restrict__ x, ushort4* __restrict__ xhi,
                               ushort4* __restrict__ xlo, int n4) {
  int stride = gridDim.x * blockDim.x;
  for (int i = blockIdx.x * blockDim.x + threadIdx.x; i < n4; i += stride) {
    float4 v = x[i];
    ushort4 h, l;
    h.x = f2bf(v.x); l.x = f2bf(v.x - bf2f(h.x));
    h.y = f2bf(v.y); l.y = f2bf(v.y - bf2f(h.y));
    h.z = f2bf(v.z); l.z = f2bf(v.z - bf2f(h.z));
    h.w = f2bf(v.w); l.w = f2bf(v.w - bf2f(h.w));
    xhi[i] = h; xlo[i] = l;
  }
}

// ---------------- transpose + split W1 -> WT (N x K) hi/lo ----------------
__global__ void split_wT_kernel(const float* __restrict__ w1, unsigned short* __restrict__ wthi,
                                unsigned short* __restrict__ wtlo) {
  __shared__ float tile[32][33];
  int bx = blockIdx.x, by = blockIdx.y;
  int tx = threadIdx.x, ty = threadIdx.y;  // (32, 8)
#pragma unroll
  for (int r = 0; r < 4; ++r) {
    int d = by * 32 + ty + r * 8;
    tile[ty + r * 8][tx] = w1[(size_t)d * NDIM + bx * 32 + tx];
  }
  __syncthreads();
#pragma unroll
  for (int r = 0; r < 4; ++r) {
    int h = bx * 32 + ty + r * 8;
    float v = tile[tx][ty + r * 8];
    unsigned short hi = f2bf(v);
    unsigned short lo = f2bf(v - bf2f(hi));
    size_t o = (size_t)h * KDIM + by * 32 + tx;
    wthi[o] = hi; wtlo[o] = lo;
  }
}

// ---------------- fused 8-phase GEMM, MFMA-first phases ----------------
// Round-4 proven schedule + relaxed vmcnt cadence (odd phases only).
// logits[m] = sum_n relu(sum_k x[m,k] W1[k,n] + b1[n]) * W2[n]
// 3-product split folded into 96 K-tiles of 64:
//   kt 0..31: xhi*wthi ; 32..63: xhi*wtlo ; 64..95: xlo*wthi
// BM=BN=256, BK=64, 8 waves. LDS ring = 8 half-tile slots (16 KB, swizzled).
// Half-tile stream per tile: [A0,B0,B1,A1]. Phase order Q00,Q01,Q11,Q10;
// each phase: STAGE -> MFMA (frags read last phase) -> fills for next phase.
// Waits: fills at phase P read halves <= P+2; vmcnt(6) at p1/p3 guarantees
// landed >= P+2 at every phase start (exact boundary at p1, slack elsewhere,
// in-order vmcnt landing + the P-1 barrier publishes cross-wave). WAR: every
// slot overwrite is >=2 barriers after its last ds_read with the consuming
// MFMA's lgkm wait in between (unchanged from round 4's proven ledger).
__global__ __launch_bounds__(512, 2) void gemm8(
    const unsigned short* __restrict__ xhi, const unsigned short* __restrict__ xlo,
    const unsigned short* __restrict__ wthi, const unsigned short* __restrict__ wtlo,
    const float* __restrict__ b1, const float* __restrict__ w2,
    float* __restrict__ part) {
  __shared__ char lds[8 * 16384];   // 128 KiB ring

  const int t = threadIdx.x;
  const int l = t & 63;
  const int w = t >> 6;
  const int sub_m = w >> 2, sub_n = w & 3;
  const int r16 = l & 15;
  const int q4 = l >> 4;

  // XCD-chunked bijective swizzle: 1024 blocks = 8 XCDs x 128
  int bid = blockIdx.x;
  int id = (bid & 7) * 128 + (bid >> 3);
  const int bm = id >> 3, bn = id & 7;
  const int m0 = bm * 256, n0 = bn * 256;

  // staging per-thread constants
  const int tr = t >> 3;                                  // 0..63
  const int cs16 = (((t & 7) ^ ((t >> 3) & 7)) << 4);     // swizzled chunk byte
  const int t16 = t << 4;

  // read-side per-thread constants
  const int axor = (l & 7) << 4;
  const int akoff = ((l >> 4) & 3) << 4;
  const int a_row0 = sub_m * 64 + (l & 15);
  const int b_row0 = sub_n * 32 + (l & 15);

#define STAGE(nn)                                                              \
  {                                                                            \
    int n_ = (nn);                                                             \
    if (n_ < 384) {                                                            \
      int jt = n_ >> 2, pos = n_ & 3;                                          \
      bool isA = (pos == 0) || (pos == 3);                                     \
      int hh = (pos >= 2) ? 1 : 0;                                             \
      const unsigned short* base =                                             \
          isA ? ((jt < 64) ? xhi : xlo)                                        \
              : ((jt < 32 || jt >= 64) ? wthi : wtlo);                         \
      int k0 = (jt & 31) << 6;                                                 \
      int row0 = (isA ? m0 : n0) + (hh << 7);                                  \
      char* dst = lds + ((n_ & 7) << 14) + t16;                                \
      const char* src = (const char*)base +                                    \
          ((((size_t)(row0 + tr)) << 11) + (size_t)k0) * 2 + cs16;             \
      gll16(src, dst);                                                         \
      gll16(src + (64ull << 12), dst + 8192);                                  \
    }                                                                          \
  }

#define LDA(slot)                                                              \
  _Pragma("unroll")                                                            \
  for (int fm = 0; fm < 4; ++fm)                                               \
    _Pragma("unroll")                                                          \
    for (int kk = 0; kk < 2; ++kk)                                             \
      a[fm][kk] = *(const bf16x8*)(lds + ((slot) << 14) +                      \
          (a_row0 + fm * 16) * 128 + (((kk << 6) | akoff) ^ axor));

#define LDB(dst, slot)                                                         \
  _Pragma("unroll")                                                            \
  for (int fn = 0; fn < 2; ++fn)                                               \
    _Pragma("unroll")                                                          \
    for (int kk = 0; kk < 2; ++kk)                                             \
      dst[fn][kk] = *(const bf16x8*)(lds + ((slot) << 14) +                    \
          (b_row0 + fn * 16) * 128 + (((kk << 6) | akoff) ^ axor));

#define MFMA16(accq, bb)                                                       \
  __builtin_amdgcn_s_setprio(1);                                               \
  _Pragma("unroll")                                                            \
  for (int fm = 0; fm < 4; ++fm)                                               \
    _Pragma("unroll")                                                          \
    for (int fn = 0; fn < 2; ++fn) {                                           \
      accq[fm][fn] = __builtin_amdgcn_mfma_f32_16x16x32_bf16(a[fm][0], bb[fn][0], accq[fm][fn], 0, 0, 0); \
      accq[fm][fn] = __builtin_amdgcn_mfma_f32_16x16x32_bf16(a[fm][1], bb[fn][1], accq[fm][fn], 0, 0, 0); \
    }                                                                          \
  __builtin_amdgcn_s_setprio(0);

#define WAITV                                                                  \
  asm volatile("s_waitcnt vmcnt(6)" ::: "memory");                             \
  __builtin_amdgcn_s_barrier();                                                \
  asm volatile("" ::: "memory");

#define WAITB                                                                  \
  __builtin_amdgcn_s_barrier();                                                \
  asm volatile("" ::: "memory");

  f32x4 acc00[4][2], acc01[4][2], acc11[4][2], acc10[4][2];
  f32x4 zero = {0.f, 0.f, 0.f, 0.f};
#pragma unroll
  for (int i = 0; i < 4; ++i)
#pragma unroll
    for (int j = 0; j < 2; ++j) {
      acc00[i][j] = zero; acc01[i][j] = zero;
      acc11[i][j] = zero; acc10[i][j] = zero;
    }

  bf16x8 a[4][2], b0f[2][2], b1f[2][2];

  // prologue (round-4 verbatim): stage H0..H6 (lead 7); vmcnt(6) -> own
  // H0..H3 landed; barrier -> ALL waves' H0..H3 landed; then frag reads
  // (consumed by p0's MFMA before p0's barrier; first overwrite of slots
  // 0/1 is STAGE(8) at p1 — 1 barrier later ✓).
  STAGE(0); STAGE(1); STAGE(2); STAGE(3); STAGE(4); STAGE(5); STAGE(6);
  asm volatile("s_waitcnt vmcnt(6)" ::: "memory");
  __builtin_amdgcn_s_barrier();
  asm volatile("" ::: "memory");
  LDA(0);          // A0 of tile 0
  LDB(b0f, 1);     // B0 of tile 0

  for (int kt = 0; kt < 96; ++kt) {
    const int sb = (kt & 1) << 2;
    const int g0 = 4 * kt;
    // p0: Q00 = A0 x B0 ; fill b1f <- B1 (slot sb+2, half g0+2 = P+2)
    STAGE(g0 + 7);
    MFMA16(acc00, b0f);
    LDB(b1f, sb + 2);
    WAITB;
    // p1: Q01 = A0 x B1 ; fill a <- A1 (slot sb+3, half g0+3 = P+2)
    STAGE(g0 + 8);
    MFMA16(acc01, b1f);
    LDA(sb + 3);
    WAITV;
    // p2: Q11 = A1 x B1 ; no fills
    STAGE(g0 + 9);
    MFMA16(acc11, b1f);
    WAITB;
    // p3: Q10 = A1 x B0 ; fill a <- A0' (half g0+4 = P+1), b0f <- B0' (P+2)
    STAGE(g0 + 10);
    MFMA16(acc10, b0f);
    LDA((sb + 4) & 7);
    LDB(b0f, (sb + 5) & 7);
    WAITV;
  }

  // drain all staging before reusing LDS
  asm volatile("s_waitcnt vmcnt(0) lgkmcnt(0)" ::: "memory");
  __builtin_amdgcn_s_barrier();
  asm volatile("" ::: "memory");

  // epilogue: relu(acc + b1) * w2, reduce over n
  float b1v[2][2], w2v[2][2];
#pragma unroll
  for (int nh = 0; nh < 2; ++nh)
#pragma unroll
    for (int fn = 0; fn < 2; ++fn) {
      int n = n0 + nh * 128 + sub_n * 32 + fn * 16 + r16;
      b1v[nh][fn] = b1[n];
      w2v[nh][fn] = w2[n];
    }

  float* red = (float*)lds;   // 4 x 256 floats
#pragma unroll
  for (int mh = 0; mh < 2; ++mh)
#pragma unroll
    for (int fm = 0; fm < 4; ++fm)
#pragma unroll
      for (int j = 0; j < 4; ++j) {
        float s = 0.f;
#pragma unroll
        for (int fn = 0; fn < 2; ++fn) {
          float h0 = (mh == 0 ? acc00[fm][fn][j] : acc10[fm][fn][j]) + b1v[0][fn];
          s += fmaxf(h0, 0.f) * w2v[0][fn];
          float h1 = (mh == 0 ? acc01[fm][fn][j] : acc11[fm][fn][j]) + b1v[1][fn];
          s += fmaxf(h1, 0.f) * w2v[1][fn];
        }
        s += __shfl_xor(s, 1);
        s += __shfl_xor(s, 2);
        s += __shfl_xor(s, 4);
        s += __shfl_xor(s, 8);
        if (r16 == 0)
          red[sub_n * 256 + mh * 128 + sub_m * 64 + fm * 16 + q4 * 4 + j] = s;
      }
  __syncthreads();
  if (t < 256) {
    float p = red[t] + red[256 + t] + red[512 + t] + red[768 + t];
    part[(size_t)(m0 + t) * 8 + bn] = p;
  }
#undef STAGE
#undef LDA
#undef LDB
#undef MFMA16
#undef WAITV
#undef WAITB
}

// ---------------- per-batch-row: expected_k, top-k mask ----------------
__global__ void rowstats(const float* __restrict__ part, const float* __restrict__ b2,
                         float* __restrict__ mask_out, float* __restrict__ ek_out) {
  __shared__ float vals[2048];
  __shared__ float srt[2048];
  __shared__ float redf[256];
  __shared__ int redi[256];
  int b = blockIdx.x, t = threadIdx.x;
  float b2v = b2[0];
  float psum = 0.f;
  for (int i = t; i < 2048; i += 256) {
    const float* pp = part + ((size_t)b * 2048 + i) * 8;
    float v = pp[0] + pp[1] + pp[2] + pp[3] + pp[4] + pp[5] + pp[6] + pp[7] + b2v;
    vals[i] = v; srt[i] = v;
    psum += 1.f / (1.f + expf(-v));
  }
  redf[t] = psum;
  __syncthreads();
  for (int s = 128; s > 0; s >>= 1) {
    if (t < s) redf[t] += redf[t + s];
    __syncthreads();
  }
  float ek = redf[0];
  int k = (int)ek;
  if (k < 32) k = 32;
  if (k > 2048) k = 2048;
  if (t == 0) ek_out[b] = ek;

  for (int ksz = 2; ksz <= 2048; ksz <<= 1) {
    for (int j = ksz >> 1; j > 0; j >>= 1) {
      for (int i = t; i < 2048; i += 256) {
        int ixj = i ^ j;
        if (ixj > i) {
          float a = srt[i], c = srt[ixj];
          bool up = ((i & ksz) == 0);
          if ((a > c) == up) { srt[i] = c; srt[ixj] = a; }
        }
      }
      __syncthreads();
    }
  }
  float thr = srt[2048 - k];

  int cnt = 0;
  for (int i = t; i < 2048; i += 256) cnt += (vals[i] > thr) ? 1 : 0;
  redi[t] = cnt;
  __syncthreads();
  for (int s = 128; s > 0; s >>= 1) {
    if (t < s) redi[t] += redi[t + s];
    __syncthreads();
  }
  int n_gt = redi[0];
  int need = k - n_gt;

  for (int i = t; i < 2048; i += 256) {
    float v = vals[i];
    float m = 0.f;
    if (v > thr) m = 1.f;
    else if (v == thr) {
      int pre = 0;
      for (int p = 0; p < i; ++p) pre += (vals[p] == thr) ? 1 : 0;
      if (pre < need) m = 1.f;
    }
    mask_out[(size_t)b * 2048 + i] = m;
  }
}

// ---------------- filtered = x * mask ----------------
__global__ void filter_k(const float4* __restrict__ x, const float* __restrict__ mask,
                         float4* __restrict__ out, int n4) {
  int stride = gridDim.x * blockDim.x;
  for (int i = blockIdx.x * blockDim.x + threadIdx.x; i < n4; i += stride) {
    float m = mask[i >> 9];
    float4 v = x[i];
    v.x *= m; v.y *= m; v.z *= m; v.w *= m;
    out[i] = v;
  }
}

extern "C" void kernel_launch(void* const* d_in, const int* in_sizes, int n_in,
                              void* d_out, int out_size, void* d_ws, size_t ws_size,
                              hipStream_t stream) {
  const float* x  = (const float*)d_in[0];
  const float* w1 = (const float*)d_in[1];
  const float* b1 = (const float*)d_in[2];
  const float* w2 = (const float*)d_in[3];
  const float* b2 = (const float*)d_in[4];

  float* out_filt = (float*)d_out;
  float* out_mask = out_filt + (size_t)67108864;
  float* out_ek   = out_mask + 32768;

  unsigned short* xhi = (unsigned short*)d_out;   // parked in out0 region

  char* wsb = (char*)d_ws;
  unsigned short* xlo  = (unsigned short*)wsb;                      // 134217728 B
  unsigned short* wthi = (unsigned short*)(wsb + 134217728);        // 8388608 B
  unsigned short* wtlo = (unsigned short*)(wsb + 142606336);        // 8388608 B
  float* part   = (float*)(wsb + 150994944);                        // 1048576 B used

  split_x_kernel<<<dim3(4096), dim3(256), 0, stream>>>(
      (const float4*)x, (ushort4*)xhi, (ushort4*)xlo, 16777216);
  split_wT_kernel<<<dim3(64, 64), dim3(32, 8), 0, stream>>>(w1, wthi, wtlo);
  gemm8<<<dim3(1024), dim3(512), 0, stream>>>(
      xhi, xlo, wthi, wtlo, b1, w2, part);
  rowstats<<<dim3(16), dim3(256), 0, stream>>>(part, b2, out_mask, out_ek);
  filter_k<<<dim3(4096), dim3(256), 0, stream>>>(
      (const float4*)x, out_mask, (float4*)out_filt, 16777216);
}

// Round 12
// 911.119 us; speedup vs baseline: 1.5593x; 1.0601x over previous
//
#include <hip/hip_runtime.h>
#include <hip/hip_bf16.h>
#include <math.h>

#define MDIM 32768
#define NDIM 2048
#define KDIM 2048

typedef __attribute__((ext_vector_type(8))) short bf16x8;
typedef __attribute__((ext_vector_type(4))) float f32x4;

__device__ __forceinline__ unsigned short f2bf(float f) {
  unsigned int u = __float_as_uint(f);
  u += 0x7FFFu + ((u >> 16) & 1u);
  return (unsigned short)(u >> 16);
}
__device__ __forceinline__ float bf2f(unsigned short b) {
  return __uint_as_float(((unsigned int)b) << 16);
}

__device__ __forceinline__ void gll16(const void* g, void* l) {
  __builtin_amdgcn_global_load_lds((__attribute__((address_space(1))) void*)g,
                                   (__attribute__((address_space(3))) void*)l,
                                   16, 0, 0);
}

// ---------------- split x into bf16 hi/lo ----------------
__global__ void split_x_kernel(const float4* __restrict__ x, ushort4* __restrict__ xhi,
                               ushort4* __restrict__ xlo, int n4) {
  int stride = gridDim.x * blockDim.x;
  for (int i = blockIdx.x * blockDim.x + threadIdx.x; i < n4; i += stride) {
    float4 v = x[i];
    ushort4 h, l;
    h.x = f2bf(v.x); l.x = f2bf(v.x - bf2f(h.x));
    h.y = f2bf(v.y); l.y = f2bf(v.y - bf2f(h.y));
    h.z = f2bf(v.z); l.z = f2bf(v.z - bf2f(h.z));
    h.w = f2bf(v.w); l.w = f2bf(v.w - bf2f(h.w));
    xhi[i] = h; xlo[i] = l;
  }
}

// ---------------- transpose + split W1 -> WT (N x K) hi/lo ----------------
__global__ void split_wT_kernel(const float* __restrict__ w1, unsigned short* __restrict__ wthi,
                                unsigned short* __restrict__ wtlo) {
  __shared__ float tile[32][33];
  int bx = blockIdx.x, by = blockIdx.y;
  int tx = threadIdx.x, ty = threadIdx.y;  // (32, 8)
#pragma unroll
  for (int r = 0; r < 4; ++r) {
    int d = by * 32 + ty + r * 8;
    tile[ty + r * 8][tx] = w1[(size_t)d * NDIM + bx * 32 + tx];
  }
  __syncthreads();
#pragma unroll
  for (int r = 0; r < 4; ++r) {
    int h = bx * 32 + ty + r * 8;
    float v = tile[tx][ty + r * 8];
    unsigned short hi = f2bf(v);
    unsigned short lo = f2bf(v - bf2f(hi));
    size_t o = (size_t)h * KDIM + by * 32 + tx;
    wthi[o] = hi; wtlo[o] = lo;
  }
}

// ---------------- fused GEMM: physical K-tiles, 3 products from regs ------
// logits[m] = sum_n relu(sum_k x[m,k] W1[k,n] + b1[n]) * W2[n]
// 64 PHYSICAL K-tiles (BK=32). Per tile the block stages 8 halves of 8 KB
// ([128 rows x 32 k] bf16, swizzled): A0h A0l B0h B0l B1h B1l A1h A1l at
// slots (kt&1)*8 + idx (16 slots = 128 KiB, slot period 2 tiles -> every
// overwrite >=5 barriers after last read). Fragments are read ONCE and all
// 3 split-products (hi*hi, hi*lo, lo*hi) run from registers: 24 ds_read +
// 96 MFMA per wave per tile (1.5x less LDS traffic than virtual-K).
// 4 phases/tile (Q00,Q01,Q11,Q10; 24 MFMA each), MFMA-first, fills after:
//   p0: stage A0'[h0,h1] ; Q00(a,b0) ; fill b1 <- B1[kt]
//   p1: stage B0'        ; Q01(a,b1) ; fill a  <- A1[kt]
//   p2: stage B1'        ; Q11(a,b1)
//   p3: stage A1'        ; Q10(a,b0) ; fill a <- A0[kt+1], b0 <- B0[kt+1]
// vmcnt(2)/phase (2 stages/phase): at each fill the most recent completed
// wait guarantees its source halves landed (b1: staged kt-1 p2, waited
// kt-1 p3; a@p1: staged kt-1 p3, waited kt p0; p3 fills: staged kt p0/p1,
// waited kt p2). Tail tile 63 peeled with vmcnt(0) (its A1 was the last
// 2 outstanding). Swizzle: read chunk q4 ^ ((r16>>1)&3), stage source
// chunk (t&3)^((t>>3)&3) — rows 0..7 spread over all 8 bank groups.
__global__ __launch_bounds__(512, 2) void gemm8(
    const unsigned short* __restrict__ xhi, const unsigned short* __restrict__ xlo,
    const unsigned short* __restrict__ wthi, const unsigned short* __restrict__ wtlo,
    const float* __restrict__ b1, const float* __restrict__ w2,
    float* __restrict__ part) {
  __shared__ char lds[16 * 8192];   // 128 KiB, 16 slots of 8 KB

  const int t = threadIdx.x;
  const int l = t & 63;
  const int w = t >> 6;
  const int sub_m = w >> 2, sub_n = w & 3;
  const int r16 = l & 15;
  const int q4 = l >> 4;

  // XCD-chunked bijective swizzle: 1024 blocks = 8 XCDs x 128
  int bid = blockIdx.x;
  int id = (bid & 7) * 128 + (bid >> 3);
  const int bm = id >> 3, bn = id & 7;
  const int m0 = bm * 256, n0 = bn * 256;

  // staging per-thread constants (8 KB half: row = t>>2, chunk = t&3)
  const int tr2 = t >> 2;                                 // 0..127
  const int cp16 = (((t & 3) ^ ((t >> 3) & 3)) << 4);     // swizzled src chunk
  const int t16 = t << 4;

  // read-side per-thread constants
  const int ardk = ((q4 ^ ((r16 >> 1) & 3)) << 4);        // swizzled read chunk
  const int a_row0 = sub_m * 64 + r16;
  const int b_row0 = sub_n * 32 + r16;

// stage half `idx` of physical tile kt_ : slot (kt_&1)*8+idx
// idx: 0:A0h 1:A0l 2:B0h 3:B0l 4:B1h 5:B1l 6:A1h 7:A1l
#define STAGE(kt_, idx)                                                        \
  {                                                                            \
    int kq_ = (kt_);                                                           \
    int slot_ = ((kq_ & 1) << 3) + (idx);                                      \
    const unsigned short* base_;                                               \
    int row0_;                                                                 \
    if ((idx) == 0)      { base_ = xhi;  row0_ = m0; }                         \
    else if ((idx) == 1) { base_ = xlo;  row0_ = m0; }                         \
    else if ((idx) == 2) { base_ = wthi; row0_ = n0; }                         \
    else if ((idx) == 3) { base_ = wtlo; row0_ = n0; }                         \
    else if ((idx) == 4) { base_ = wthi; row0_ = n0 + 128; }                   \
    else if ((idx) == 5) { base_ = wtlo; row0_ = n0 + 128; }                   \
    else if ((idx) == 6) { base_ = xhi;  row0_ = m0 + 128; }                   \
    else                 { base_ = xlo;  row0_ = m0 + 128; }                   \
    char* dst_ = lds + (slot_ << 13) + t16;                                    \
    const char* src_ = (const char*)base_ +                                    \
        (((size_t)(row0_ + tr2)) << 12) + (size_t)(kq_ << 6) + cp16;           \
    gll16(src_, dst_);                                                         \
  }

// a[fm][0] <- hi half (slot), a[fm][1] <- lo half (slot+1)
#define LDA(slotA)                                                             \
  _Pragma("unroll")                                                            \
  for (int fm = 0; fm < 4; ++fm) {                                             \
    int row_ = a_row0 + fm * 16;                                               \
    a[fm][0] = *(const bf16x8*)(lds + ((slotA) << 13) + row_ * 64 + ardk);     \
    a[fm][1] = *(const bf16x8*)(lds + (((slotA) + 1) << 13) + row_ * 64 + ardk); \
  }

#define LDB(dst, slotB)                                                        \
  _Pragma("unroll")                                                            \
  for (int fn = 0; fn < 2; ++fn) {                                             \
    int row_ = b_row0 + fn * 16;                                               \
    dst[fn][0] = *(const bf16x8*)(lds + ((slotB) << 13) + row_ * 64 + ardk);   \
    dst[fn][1] = *(const bf16x8*)(lds + (((slotB) + 1) << 13) + row_ * 64 + ardk); \
  }

// 24 MFMA: 3 split-products per (fm, fn)
#define MFMA24(accq, bb)                                                       \
  __builtin_amdgcn_s_setprio(1);                                               \
  _Pragma("unroll")                                                            \
  for (int fm = 0; fm < 4; ++fm)                                               \
    _Pragma("unroll")                                                          \
    for (int fn = 0; fn < 2; ++fn) {                                           \
      accq[fm][fn] = __builtin_amdgcn_mfma_f32_16x16x32_bf16(a[fm][0], bb[fn][0], accq[fm][fn], 0, 0, 0); \
      accq[fm][fn] = __builtin_amdgcn_mfma_f32_16x16x32_bf16(a[fm][0], bb[fn][1], accq[fm][fn], 0, 0, 0); \
      accq[fm][fn] = __builtin_amdgcn_mfma_f32_16x16x32_bf16(a[fm][1], bb[fn][0], accq[fm][fn], 0, 0, 0); \
    }                                                                          \
  __builtin_amdgcn_s_setprio(0);

#define WAITBAR                                                                \
  asm volatile("s_waitcnt vmcnt(2)" ::: "memory");                             \
  __builtin_amdgcn_s_barrier();                                                \
  asm volatile("" ::: "memory");

  f32x4 acc00[4][2], acc01[4][2], acc11[4][2], acc10[4][2];
  f32x4 zero = {0.f, 0.f, 0.f, 0.f};
#pragma unroll
  for (int i = 0; i < 4; ++i)
#pragma unroll
    for (int j = 0; j < 2; ++j) {
      acc00[i][j] = zero; acc01[i][j] = zero;
      acc11[i][j] = zero; acc10[i][j] = zero;
    }

  bf16x8 a[4][2], b0f[2][2], b1f[2][2];

  // prologue: stage all 8 halves of tile 0; vmcnt(0)+barrier -> all waves'
  // halves landed (vmcnt is per-wave, slots written cooperatively); read
  // initial fragments. First loop stage writes opposite-parity slots 8,9.
  STAGE(0, 0); STAGE(0, 1); STAGE(0, 2); STAGE(0, 3);
  STAGE(0, 4); STAGE(0, 5); STAGE(0, 6); STAGE(0, 7);
  asm volatile("s_waitcnt vmcnt(0)" ::: "memory");
  __builtin_amdgcn_s_barrier();
  asm volatile("" ::: "memory");
  LDA(0);          // A0[0] (hi,lo)
  LDB(b0f, 2);     // B0[0]

  for (int kt = 0; kt < 63; ++kt) {
    const int sb = (kt & 1) << 3;
    const int sn = ((kt + 1) & 1) << 3;
    const int nx = kt + 1;
    // p0: Q00 = A0 x B0 ; fill b1 <- B1[kt] (staged kt-1 p2, waited kt-1 p3)
    STAGE(nx, 0); STAGE(nx, 1);
    MFMA24(acc00, b0f);
    LDB(b1f, sb + 4);
    WAITBAR;
    // p1: Q01 = A0 x B1 ; fill a <- A1[kt] (staged kt-1 p3, waited kt p0)
    STAGE(nx, 2); STAGE(nx, 3);
    MFMA24(acc01, b1f);
    LDA(sb + 6);
    WAITBAR;
    // p2: Q11 = A1 x B1
    STAGE(nx, 4); STAGE(nx, 5);
    MFMA24(acc11, b1f);
    WAITBAR;
    // p3: Q10 = A1 x B0 ; fill a <- A0[kt+1], b0 <- B0[kt+1] (staged kt
    // p0/p1, waited kt p2)
    STAGE(nx, 6); STAGE(nx, 7);
    MFMA24(acc10, b0f);
    LDA(sn);
    LDB(b0f, sn + 2);
    WAITBAR;
  }

  // tail: tile 63 (slots 8..15), no next-tile stages/fills.
  {
    const int sb = 8;
    // B1[63] staged kt=62 p2 -> landed by kt=62 p3's vmcnt(2) ✓
    MFMA24(acc00, b0f);
    LDB(b1f, sb + 4);
    // A1[63] staged kt=62 p3 = the last 2 outstanding -> drain fully
    asm volatile("s_waitcnt vmcnt(0)" ::: "memory");
    __builtin_amdgcn_s_barrier();
    asm volatile("" ::: "memory");
    MFMA24(acc01, b1f);
    LDA(sb + 6);
    MFMA24(acc11, b1f);
    MFMA24(acc10, b0f);
  }

  // drain before reusing LDS
  asm volatile("s_waitcnt vmcnt(0) lgkmcnt(0)" ::: "memory");
  __builtin_amdgcn_s_barrier();
  asm volatile("" ::: "memory");

  // epilogue: relu(acc + b1) * w2, reduce over n
  float b1v[2][2], w2v[2][2];
#pragma unroll
  for (int nh = 0; nh < 2; ++nh)
#pragma unroll
    for (int fn = 0; fn < 2; ++fn) {
      int n = n0 + nh * 128 + sub_n * 32 + fn * 16 + r16;
      b1v[nh][fn] = b1[n];
      w2v[nh][fn] = w2[n];
    }

  float* red = (float*)lds;   // 4 x 256 floats
#pragma unroll
  for (int mh = 0; mh < 2; ++mh)
#pragma unroll
    for (int fm = 0; fm < 4; ++fm)
#pragma unroll
      for (int j = 0; j < 4; ++j) {
        float s = 0.f;
#pragma unroll
        for (int fn = 0; fn < 2; ++fn) {
          float h0 = (mh == 0 ? acc00[fm][fn][j] : acc10[fm][fn][j]) + b1v[0][fn];
          s += fmaxf(h0, 0.f) * w2v[0][fn];
          float h1 = (mh == 0 ? acc01[fm][fn][j] : acc11[fm][fn][j]) + b1v[1][fn];
          s += fmaxf(h1, 0.f) * w2v[1][fn];
        }
        s += __shfl_xor(s, 1);
        s += __shfl_xor(s, 2);
        s += __shfl_xor(s, 4);
        s += __shfl_xor(s, 8);
        if (r16 == 0)
          red[sub_n * 256 + mh * 128 + sub_m * 64 + fm * 16 + q4 * 4 + j] = s;
      }
  __syncthreads();
  if (t < 256) {
    float p = red[t] + red[256 + t] + red[512 + t] + red[768 + t];
    part[(size_t)(m0 + t) * 8 + bn] = p;
  }
#undef STAGE
#undef LDA
#undef LDB
#undef MFMA24
#undef WAITBAR
}

// ---------------- per-batch-row: expected_k, top-k mask ----------------
__global__ void rowstats(const float* __restrict__ part, const float* __restrict__ b2,
                         float* __restrict__ mask_out, float* __restrict__ ek_out) {
  __shared__ float vals[2048];
  __shared__ float srt[2048];
  __shared__ float redf[256];
  __shared__ int redi[256];
  int b = blockIdx.x, t = threadIdx.x;
  float b2v = b2[0];
  float psum = 0.f;
  for (int i = t; i < 2048; i += 256) {
    const float* pp = part + ((size_t)b * 2048 + i) * 8;
    float v = pp[0] + pp[1] + pp[2] + pp[3] + pp[4] + pp[5] + pp[6] + pp[7] + b2v;
    vals[i] = v; srt[i] = v;
    psum += 1.f / (1.f + expf(-v));
  }
  redf[t] = psum;
  __syncthreads();
  for (int s = 128; s > 0; s >>= 1) {
    if (t < s) redf[t] += redf[t + s];
    __syncthreads();
  }
  float ek = redf[0];
  int k = (int)ek;
  if (k < 32) k = 32;
  if (k > 2048) k = 2048;
  if (t == 0) ek_out[b] = ek;

  for (int ksz = 2; ksz <= 2048; ksz <<= 1) {
    for (int j = ksz >> 1; j > 0; j >>= 1) {
      for (int i = t; i < 2048; i += 256) {
        int ixj = i ^ j;
        if (ixj > i) {
          float a = srt[i], c = srt[ixj];
          bool up = ((i & ksz) == 0);
          if ((a > c) == up) { srt[i] = c; srt[ixj] = a; }
        }
      }
      __syncthreads();
    }
  }
  float thr = srt[2048 - k];

  int cnt = 0;
  for (int i = t; i < 2048; i += 256) cnt += (vals[i] > thr) ? 1 : 0;
  redi[t] = cnt;
  __syncthreads();
  for (int s = 128; s > 0; s >>= 1) {
    if (t < s) redi[t] += redi[t + s];
    __syncthreads();
  }
  int n_gt = redi[0];
  int need = k - n_gt;

  for (int i = t; i < 2048; i += 256) {
    float v = vals[i];
    float m = 0.f;
    if (v > thr) m = 1.f;
    else if (v == thr) {
      int pre = 0;
      for (int p = 0; p < i; ++p) pre += (vals[p] == thr) ? 1 : 0;
      if (pre < need) m = 1.f;
    }
    mask_out[(size_t)b * 2048 + i] = m;
  }
}

// ---------------- filtered = x * mask ----------------
__global__ void filter_k(const float4* __restrict__ x, const float* __restrict__ mask,
                         float4* __restrict__ out, int n4) {
  int stride = gridDim.x * blockDim.x;
  for (int i = blockIdx.x * blockDim.x + threadIdx.x; i < n4; i += stride) {
    float m = mask[i >> 9];
    float4 v = x[i];
    v.x *= m; v.y *= m; v.z *= m; v.w *= m;
    out[i] = v;
  }
}

extern "C" void kernel_launch(void* const* d_in, const int* in_sizes, int n_in,
                              void* d_out, int out_size, void* d_ws, size_t ws_size,
                              hipStream_t stream) {
  const float* x  = (const float*)d_in[0];
  const float* w1 = (const float*)d_in[1];
  const float* b1 = (const float*)d_in[2];
  const float* w2 = (const float*)d_in[3];
  const float* b2 = (const float*)d_in[4];

  float* out_filt = (float*)d_out;
  float* out_mask = out_filt + (size_t)67108864;
  float* out_ek   = out_mask + 32768;

  unsigned short* xhi = (unsigned short*)d_out;   // parked in out0 region

  char* wsb = (char*)d_ws;
  unsigned short* xlo  = (unsigned short*)wsb;                      // 134217728 B
  unsigned short* wthi = (unsigned short*)(wsb + 134217728);        // 8388608 B
  unsigned short* wtlo = (unsigned short*)(wsb + 142606336);        // 8388608 B
  float* part   = (float*)(wsb + 150994944);                        // 1048576 B used

  split_x_kernel<<<dim3(4096), dim3(256), 0, stream>>>(
      (const float4*)x, (ushort4*)xhi, (ushort4*)xlo, 16777216);
  split_wT_kernel<<<dim3(64, 64), dim3(32, 8), 0, stream>>>(w1, wthi, wtlo);
  gemm8<<<dim3(1024), dim3(512), 0, stream>>>(
      xhi, xlo, wthi, wtlo, b1, w2, part);
  rowstats<<<dim3(16), dim3(256), 0, stream>>>(part, b2, out_mask, out_ek);
  filter_k<<<dim3(4096), dim3(256), 0, stream>>>(
      (const float4*)x, out_mask, (float4*)out_filt, 16777216);
}

// Round 13
// 906.861 us; speedup vs baseline: 1.5666x; 1.0047x over previous
//
#include <hip/hip_runtime.h>
#include <hip/hip_bf16.h>
#include <math.h>

#define MDIM 32768
#define NDIM 2048
#define KDIM 2048

typedef __attribute__((ext_vector_type(8))) short bf16x8;
typedef __attribute__((ext_vector_type(4))) float f32x4;

__device__ __forceinline__ unsigned short f2bf(float f) {
  unsigned int u = __float_as_uint(f);
  u += 0x7FFFu + ((u >> 16) & 1u);
  return (unsigned short)(u >> 16);
}
__device__ __forceinline__ float bf2f(unsigned short b) {
  return __uint_as_float(((unsigned int)b) << 16);
}

__device__ __forceinline__ void gll16(const void* g, void* l) {
  __builtin_amdgcn_global_load_lds((__attribute__((address_space(1))) void*)g,
                                   (__attribute__((address_space(3))) void*)l,
                                   16, 0, 0);
}

// ---------------- split x into bf16 hi/lo (2-way unrolled, coalesced) ------
__global__ void split_x_kernel(const float4* __restrict__ x, ushort4* __restrict__ xhi,
                               ushort4* __restrict__ xlo, int n4) {
  int step = gridDim.x * blockDim.x * 2;
  for (int base = blockIdx.x * blockDim.x * 2; base < n4; base += step) {
    int i0 = base + threadIdx.x;
    int i1 = i0 + blockDim.x;
    float4 v0 = x[i0];
    float4 v1 = x[i1];
    ushort4 h0, l0, h1, l1;
    h0.x = f2bf(v0.x); l0.x = f2bf(v0.x - bf2f(h0.x));
    h0.y = f2bf(v0.y); l0.y = f2bf(v0.y - bf2f(h0.y));
    h0.z = f2bf(v0.z); l0.z = f2bf(v0.z - bf2f(h0.z));
    h0.w = f2bf(v0.w); l0.w = f2bf(v0.w - bf2f(h0.w));
    h1.x = f2bf(v1.x); l1.x = f2bf(v1.x - bf2f(h1.x));
    h1.y = f2bf(v1.y); l1.y = f2bf(v1.y - bf2f(h1.y));
    h1.z = f2bf(v1.z); l1.z = f2bf(v1.z - bf2f(h1.z));
    h1.w = f2bf(v1.w); l1.w = f2bf(v1.w - bf2f(h1.w));
    xhi[i0] = h0; xlo[i0] = l0;
    xhi[i1] = h1; xlo[i1] = l1;
  }
}

// ---------------- transpose + split W1 -> WT (N x K) hi/lo ----------------
__global__ void split_wT_kernel(const float* __restrict__ w1, unsigned short* __restrict__ wthi,
                                unsigned short* __restrict__ wtlo) {
  __shared__ float tile[32][33];
  int bx = blockIdx.x, by = blockIdx.y;
  int tx = threadIdx.x, ty = threadIdx.y;  // (32, 8)
#pragma unroll
  for (int r = 0; r < 4; ++r) {
    int d = by * 32 + ty + r * 8;
    tile[ty + r * 8][tx] = w1[(size_t)d * NDIM + bx * 32 + tx];
  }
  __syncthreads();
#pragma unroll
  for (int r = 0; r < 4; ++r) {
    int h = bx * 32 + ty + r * 8;
    float v = tile[tx][ty + r * 8];
    unsigned short hi = f2bf(v);
    unsigned short lo = f2bf(v - bf2f(hi));
    size_t o = (size_t)h * KDIM + by * 32 + tx;
    wthi[o] = hi; wtlo[o] = lo;
  }
}

// ---------------- fused GEMM: physical K-tiles, 3 products from regs ------
// (R12 structure; single change: b1f fill HOISTED to p0 start — b1f's last
// consumer Q11 issued at p2(kt-1), source B1[kt] staged p2(kt-1) landed by
// p3(kt-1)'s vmcnt(2)+barrier, so the 4 ds_reads overlap Q00's MFMA cluster
// instead of sitting exposed at p0's end. All other fills are register-
// blocked from hoisting (244/256 VGPR+AGPR used; +48 for double-buffer
// would spill — R8).
__global__ __launch_bounds__(512, 2) void gemm8(
    const unsigned short* __restrict__ xhi, const unsigned short* __restrict__ xlo,
    const unsigned short* __restrict__ wthi, const unsigned short* __restrict__ wtlo,
    const float* __restrict__ b1, const float* __restrict__ w2,
    float* __restrict__ part) {
  __shared__ char lds[16 * 8192];   // 128 KiB, 16 slots of 8 KB

  const int t = threadIdx.x;
  const int l = t & 63;
  const int w = t >> 6;
  const int sub_m = w >> 2, sub_n = w & 3;
  const int r16 = l & 15;
  const int q4 = l >> 4;

  // XCD-chunked bijective swizzle: 1024 blocks = 8 XCDs x 128
  int bid = blockIdx.x;
  int id = (bid & 7) * 128 + (bid >> 3);
  const int bm = id >> 3, bn = id & 7;
  const int m0 = bm * 256, n0 = bn * 256;

  // staging per-thread constants (8 KB half: row = t>>2, chunk = t&3)
  const int tr2 = t >> 2;                                 // 0..127
  const int cp16 = (((t & 3) ^ ((t >> 3) & 3)) << 4);     // swizzled src chunk
  const int t16 = t << 4;

  // read-side per-thread constants
  const int ardk = ((q4 ^ ((r16 >> 1) & 3)) << 4);        // swizzled read chunk
  const int a_row0 = sub_m * 64 + r16;
  const int b_row0 = sub_n * 32 + r16;

// stage half `idx` of physical tile kt_ : slot (kt_&1)*8+idx
// idx: 0:A0h 1:A0l 2:B0h 3:B0l 4:B1h 5:B1l 6:A1h 7:A1l
#define STAGE(kt_, idx)                                                        \
  {                                                                            \
    int kq_ = (kt_);                                                           \
    int slot_ = ((kq_ & 1) << 3) + (idx);                                      \
    const unsigned short* base_;                                               \
    int row0_;                                                                 \
    if ((idx) == 0)      { base_ = xhi;  row0_ = m0; }                         \
    else if ((idx) == 1) { base_ = xlo;  row0_ = m0; }                         \
    else if ((idx) == 2) { base_ = wthi; row0_ = n0; }                         \
    else if ((idx) == 3) { base_ = wtlo; row0_ = n0; }                         \
    else if ((idx) == 4) { base_ = wthi; row0_ = n0 + 128; }                   \
    else if ((idx) == 5) { base_ = wtlo; row0_ = n0 + 128; }                   \
    else if ((idx) == 6) { base_ = xhi;  row0_ = m0 + 128; }                   \
    else                 { base_ = xlo;  row0_ = m0 + 128; }                   \
    char* dst_ = lds + (slot_ << 13) + t16;                                    \
    const char* src_ = (const char*)base_ +                                    \
        (((size_t)(row0_ + tr2)) << 12) + (size_t)(kq_ << 6) + cp16;           \
    gll16(src_, dst_);                                                         \
  }

// a[fm][0] <- hi half (slot), a[fm][1] <- lo half (slot+1)
#define LDA(slotA)                                                             \
  _Pragma("unroll")                                                            \
  for (int fm = 0; fm < 4; ++fm) {                                             \
    int row_ = a_row0 + fm * 16;                                               \
    a[fm][0] = *(const bf16x8*)(lds + ((slotA) << 13) + row_ * 64 + ardk);     \
    a[fm][1] = *(const bf16x8*)(lds + (((slotA) + 1) << 13) + row_ * 64 + ardk); \
  }

#define LDB(dst, slotB)                                                        \
  _Pragma("unroll")                                                            \
  for (int fn = 0; fn < 2; ++fn) {                                             \
    int row_ = b_row0 + fn * 16;                                               \
    dst[fn][0] = *(const bf16x8*)(lds + ((slotB) << 13) + row_ * 64 + ardk);   \
    dst[fn][1] = *(const bf16x8*)(lds + (((slotB) + 1) << 13) + row_ * 64 + ardk); \
  }

// 24 MFMA: 3 split-products per (fm, fn)
#define MFMA24(accq, bb)                                                       \
  __builtin_amdgcn_s_setprio(1);                                               \
  _Pragma("unroll")                                                            \
  for (int fm = 0; fm < 4; ++fm)                                               \
    _Pragma("unroll")                                                          \
    for (int fn = 0; fn < 2; ++fn) {                                           \
      accq[fm][fn] = __builtin_amdgcn_mfma_f32_16x16x32_bf16(a[fm][0], bb[fn][0], accq[fm][fn], 0, 0, 0); \
      accq[fm][fn] = __builtin_amdgcn_mfma_f32_16x16x32_bf16(a[fm][0], bb[fn][1], accq[fm][fn], 0, 0, 0); \
      accq[fm][fn] = __builtin_amdgcn_mfma_f32_16x16x32_bf16(a[fm][1], bb[fn][0], accq[fm][fn], 0, 0, 0); \
    }                                                                          \
  __builtin_amdgcn_s_setprio(0);

#define WAITBAR                                                                \
  asm volatile("s_waitcnt vmcnt(2)" ::: "memory");                             \
  __builtin_amdgcn_s_barrier();                                                \
  asm volatile("" ::: "memory");

  f32x4 acc00[4][2], acc01[4][2], acc11[4][2], acc10[4][2];
  f32x4 zero = {0.f, 0.f, 0.f, 0.f};
#pragma unroll
  for (int i = 0; i < 4; ++i)
#pragma unroll
    for (int j = 0; j < 2; ++j) {
      acc00[i][j] = zero; acc01[i][j] = zero;
      acc11[i][j] = zero; acc10[i][j] = zero;
    }

  bf16x8 a[4][2], b0f[2][2], b1f[2][2];

  // prologue: stage all 8 halves of tile 0; vmcnt(0)+barrier -> all waves'
  // halves landed (vmcnt is per-wave, slots written cooperatively); read
  // initial fragments. First loop stage writes opposite-parity slots 8,9.
  STAGE(0, 0); STAGE(0, 1); STAGE(0, 2); STAGE(0, 3);
  STAGE(0, 4); STAGE(0, 5); STAGE(0, 6); STAGE(0, 7);
  asm volatile("s_waitcnt vmcnt(0)" ::: "memory");
  __builtin_amdgcn_s_barrier();
  asm volatile("" ::: "memory");
  LDA(0);          // A0[0] (hi,lo)
  LDB(b0f, 2);     // B0[0]

  for (int kt = 0; kt < 63; ++kt) {
    const int sb = (kt & 1) << 3;
    const int sn = ((kt + 1) & 1) << 3;
    const int nx = kt + 1;
    // p0: HOISTED fill b1f <- B1[kt] (staged kt-1 p2, landed by kt-1 p3's
    // wait; b1f regs free — last consumed by Q11 at p2(kt-1)); reads hide
    // under Q00's MFMA cluster.
    LDB(b1f, sb + 4);
    STAGE(nx, 0); STAGE(nx, 1);
    MFMA24(acc00, b0f);
    WAITBAR;
    // p1: Q01 = A0 x B1 ; fill a <- A1[kt] (a in use by Q01 -> post-MFMA)
    STAGE(nx, 2); STAGE(nx, 3);
    MFMA24(acc01, b1f);
    LDA(sb + 6);
    WAITBAR;
    // p2: Q11 = A1 x B1
    STAGE(nx, 4); STAGE(nx, 5);
    MFMA24(acc11, b1f);
    WAITBAR;
    // p3: Q10 = A1 x B0 ; fills a <- A0[kt+1], b0 <- B0[kt+1] (staged kt
    // p0/p1, waited kt p2; both reg sets in use by Q10/Q11 -> post-MFMA)
    STAGE(nx, 6); STAGE(nx, 7);
    MFMA24(acc10, b0f);
    LDA(sn);
    LDB(b0f, sn + 2);
    WAITBAR;
  }

  // tail: tile 63 (slots 8..15), no next-tile stages/fills.
  {
    const int sb = 8;
    // B1[63] staged kt=62 p2 -> landed by kt=62 p3's vmcnt(2); hoisted.
    LDB(b1f, sb + 4);
    MFMA24(acc00, b0f);
    // A1[63] staged kt=62 p3 = the last 2 outstanding -> drain fully
    asm volatile("s_waitcnt vmcnt(0)" ::: "memory");
    __builtin_amdgcn_s_barrier();
    asm volatile("" ::: "memory");
    MFMA24(acc01, b1f);
    LDA(sb + 6);
    MFMA24(acc11, b1f);
    MFMA24(acc10, b0f);
  }

  // drain before reusing LDS
  asm volatile("s_waitcnt vmcnt(0) lgkmcnt(0)" ::: "memory");
  __builtin_amdgcn_s_barrier();
  asm volatile("" ::: "memory");

  // epilogue: relu(acc + b1) * w2, reduce over n
  float b1v[2][2], w2v[2][2];
#pragma unroll
  for (int nh = 0; nh < 2; ++nh)
#pragma unroll
    for (int fn = 0; fn < 2; ++fn) {
      int n = n0 + nh * 128 + sub_n * 32 + fn * 16 + r16;
      b1v[nh][fn] = b1[n];
      w2v[nh][fn] = w2[n];
    }

  float* red = (float*)lds;   // 4 x 256 floats
#pragma unroll
  for (int mh = 0; mh < 2; ++mh)
#pragma unroll
    for (int fm = 0; fm < 4; ++fm)
#pragma unroll
      for (int j = 0; j < 4; ++j) {
        float s = 0.f;
#pragma unroll
        for (int fn = 0; fn < 2; ++fn) {
          float h0 = (mh == 0 ? acc00[fm][fn][j] : acc10[fm][fn][j]) + b1v[0][fn];
          s += fmaxf(h0, 0.f) * w2v[0][fn];
          float h1 = (mh == 0 ? acc01[fm][fn][j] : acc11[fm][fn][j]) + b1v[1][fn];
          s += fmaxf(h1, 0.f) * w2v[1][fn];
        }
        s += __shfl_xor(s, 1);
        s += __shfl_xor(s, 2);
        s += __shfl_xor(s, 4);
        s += __shfl_xor(s, 8);
        if (r16 == 0)
          red[sub_n * 256 + mh * 128 + sub_m * 64 + fm * 16 + q4 * 4 + j] = s;
      }
  __syncthreads();
  if (t < 256) {
    float p = red[t] + red[256 + t] + red[512 + t] + red[768 + t];
    part[(size_t)(m0 + t) * 8 + bn] = p;
  }
#undef STAGE
#undef LDA
#undef LDB
#undef MFMA24
#undef WAITBAR
}

// ---------------- per-batch-row: expected_k, top-k mask ----------------
__global__ void rowstats(const float* __restrict__ part, const float* __restrict__ b2,
                         float* __restrict__ mask_out, float* __restrict__ ek_out) {
  __shared__ float vals[2048];
  __shared__ float srt[2048];
  __shared__ float redf[256];
  __shared__ int redi[256];
  int b = blockIdx.x, t = threadIdx.x;
  float b2v = b2[0];
  float psum = 0.f;
  for (int i = t; i < 2048; i += 256) {
    const float* pp = part + ((size_t)b * 2048 + i) * 8;
    float v = pp[0] + pp[1] + pp[2] + pp[3] + pp[4] + pp[5] + pp[6] + pp[7] + b2v;
    vals[i] = v; srt[i] = v;
    psum += 1.f / (1.f + expf(-v));
  }
  redf[t] = psum;
  __syncthreads();
  for (int s = 128; s > 0; s >>= 1) {
    if (t < s) redf[t] += redf[t + s];
    __syncthreads();
  }
  float ek = redf[0];
  int k = (int)ek;
  if (k < 32) k = 32;
  if (k > 2048) k = 2048;
  if (t == 0) ek_out[b] = ek;

  for (int ksz = 2; ksz <= 2048; ksz <<= 1) {
    for (int j = ksz >> 1; j > 0; j >>= 1) {
      for (int i = t; i < 2048; i += 256) {
        int ixj = i ^ j;
        if (ixj > i) {
          float a = srt[i], c = srt[ixj];
          bool up = ((i & ksz) == 0);
          if ((a > c) == up) { srt[i] = c; srt[ixj] = a; }
        }
      }
      __syncthreads();
    }
  }
  float thr = srt[2048 - k];

  int cnt = 0;
  for (int i = t; i < 2048; i += 256) cnt += (vals[i] > thr) ? 1 : 0;
  redi[t] = cnt;
  __syncthreads();
  for (int s = 128; s > 0; s >>= 1) {
    if (t < s) redi[t] += redi[t + s];
    __syncthreads();
  }
  int n_gt = redi[0];
  int need = k - n_gt;

  for (int i = t; i < 2048; i += 256) {
    float v = vals[i];
    float m = 0.f;
    if (v > thr) m = 1.f;
    else if (v == thr) {
      int pre = 0;
      for (int p = 0; p < i; ++p) pre += (vals[p] == thr) ? 1 : 0;
      if (pre < need) m = 1.f;
    }
    mask_out[(size_t)b * 2048 + i] = m;
  }
}

// ---------------- filtered = x * mask (2-way unrolled, coalesced) ----------
__global__ void filter_k(const float4* __restrict__ x, const float* __restrict__ mask,
                         float4* __restrict__ out, int n4) {
  int step = gridDim.x * blockDim.x * 2;
  for (int base = blockIdx.x * blockDim.x * 2; base < n4; base += step) {
    int i0 = base + threadIdx.x;
    int i1 = i0 + blockDim.x;
    float m0 = mask[i0 >> 9];
    float m1 = mask[i1 >> 9];
    float4 v0 = x[i0];
    float4 v1 = x[i1];
    v0.x *= m0; v0.y *= m0; v0.z *= m0; v0.w *= m0;
    v1.x *= m1; v1.y *= m1; v1.z *= m1; v1.w *= m1;
    out[i0] = v0;
    out[i1] = v1;
  }
}

extern "C" void kernel_launch(void* const* d_in, const int* in_sizes, int n_in,
                              void* d_out, int out_size, void* d_ws, size_t ws_size,
                              hipStream_t stream) {
  const float* x  = (const float*)d_in[0];
  const float* w1 = (const float*)d_in[1];
  const float* b1 = (const float*)d_in[2];
  const float* w2 = (const float*)d_in[3];
  const float* b2 = (const float*)d_in[4];

  float* out_filt = (float*)d_out;
  float* out_mask = out_filt + (size_t)67108864;
  float* out_ek   = out_mask + 32768;

  unsigned short* xhi = (unsigned short*)d_out;   // parked in out0 region

  char* wsb = (char*)d_ws;
  unsigned short* xlo  = (unsigned short*)wsb;                      // 134217728 B
  unsigned short* wthi = (unsigned short*)(wsb + 134217728);        // 8388608 B
  unsigned short* wtlo = (unsigned short*)(wsb + 142606336);        // 8388608 B
  float* part   = (float*)(wsb + 150994944);                        // 1048576 B used

  split_x_kernel<<<dim3(2048), dim3(256), 0, stream>>>(
      (const float4*)x, (ushort4*)xhi, (ushort4*)xlo, 16777216);
  split_wT_kernel<<<dim3(64, 64), dim3(32, 8), 0, stream>>>(w1, wthi, wtlo);
  gemm8<<<dim3(1024), dim3(512), 0, stream>>>(
      xhi, xlo, wthi, wtlo, b1, w2, part);
  rowstats<<<dim3(16), dim3(256), 0, stream>>>(part, b2, out_mask, out_ek);
  filter_k<<<dim3(2048), dim3(256), 0, stream>>>(
      (const float4*)x, out_mask, (float4*)out_filt, 16777216);
}